// Round 1
// baseline (276.087 us; speedup 1.0000x reference)
//
#include <hip/hip_runtime.h>
#include <math.h>

#define BLOCK 256
#define GRID 2048

// Stage 1: grid-stride float4 loads, per-thread accumulate (x-y)^2,
// wave shuffle reduce -> LDS -> one float partial per block into d_ws.
__global__ __launch_bounds__(BLOCK) void partial_sq_sum(
    const float4* __restrict__ a, const float4* __restrict__ b,
    float* __restrict__ partial, int n4) {
    int tid = blockIdx.x * BLOCK + threadIdx.x;
    int stride = gridDim.x * BLOCK;
    float acc = 0.0f;
    for (int i = tid; i < n4; i += stride) {
        float4 x = a[i];
        float4 y = b[i];
        float d0 = x.x - y.x;
        float d1 = x.y - y.y;
        float d2 = x.z - y.z;
        float d3 = x.w - y.w;
        acc += d0 * d0 + d1 * d1 + d2 * d2 + d3 * d3;
    }
    // wave-64 reduction
    #pragma unroll
    for (int off = 32; off > 0; off >>= 1)
        acc += __shfl_down(acc, off, 64);
    __shared__ float smem[BLOCK / 64];
    int lane = threadIdx.x & 63;
    int wave = threadIdx.x >> 6;
    if (lane == 0) smem[wave] = acc;
    __syncthreads();
    if (threadIdx.x == 0) {
        float s = 0.0f;
        #pragma unroll
        for (int w = 0; w < BLOCK / 64; ++w) s += smem[w];
        partial[blockIdx.x] = s;
    }
}

// Stage 2: one block sums the GRID partials, applies the exact-match
// element-0 correction ((0.8*d0)^2 - d0^2 iff d0 in {3,4,5,6}), divides by N.
__global__ __launch_bounds__(BLOCK) void finalize(
    const float* __restrict__ partial, int n_partial,
    const float* __restrict__ in0, const float* __restrict__ tg0,
    float* __restrict__ out, float inv_n) {
    float acc = 0.0f;
    for (int i = threadIdx.x; i < n_partial; i += BLOCK)
        acc += partial[i];
    #pragma unroll
    for (int off = 32; off > 0; off >>= 1)
        acc += __shfl_down(acc, off, 64);
    __shared__ float smem[BLOCK / 64];
    int lane = threadIdx.x & 63;
    int wave = threadIdx.x >> 6;
    if (lane == 0) smem[wave] = acc;
    __syncthreads();
    if (threadIdx.x == 0) {
        float s = 0.0f;
        #pragma unroll
        for (int w = 0; w < BLOCK / 64; ++w) s += smem[w];
        float d0 = fabsf(in0[0] - tg0[0]);
        if (d0 == 3.0f || d0 == 4.0f || d0 == 5.0f || d0 == 6.0f) {
            float d0s = 0.8f * d0;
            s += d0s * d0s - d0 * d0;
        }
        out[0] = s * inv_n;
    }
}

extern "C" void kernel_launch(void* const* d_in, const int* in_sizes, int n_in,
                              void* d_out, int out_size, void* d_ws, size_t ws_size,
                              hipStream_t stream) {
    const float* input  = (const float*)d_in[0];
    const float* target = (const float*)d_in[1];
    float* out = (float*)d_out;
    float* partial = (float*)d_ws;  // GRID floats of scratch

    int n = in_sizes[0];          // 33554432
    int n4 = n >> 2;              // float4 count (N divisible by 4)

    partial_sq_sum<<<GRID, BLOCK, 0, stream>>>(
        (const float4*)input, (const float4*)target, partial, n4);
    finalize<<<1, BLOCK, 0, stream>>>(
        partial, GRID, input, target, out, 1.0f / (float)n);
}